// Round 9
// baseline (505.985 us; speedup 1.0000x reference)
//
#include <hip/hip_runtime.h>

// ---------------------------------------------------------------------------
// EdgeLLMAttentionTRTNative: fused qkv-proj + rmsnorm + rope + cache update +
// GQA causal attention (group-summed) + o-proj.   I/O is FP32 (per reference);
// compute internally in bf16 MFMA with fp32 accumulation.
//
// Shapes: B=2 Q=1024 PAST=1024 MAXC=4096 H=32 HKV=8 D=128 HID=4096
// d_out (fp32) = [attn (2,1024,4096) | present_k (2,8,4096,128) | present_v]
// ---------------------------------------------------------------------------

typedef __bf16 bf16;
typedef __attribute__((ext_vector_type(8))) __bf16 bf16x8;
typedef __attribute__((ext_vector_type(4))) __bf16 bf16x4;
typedef __attribute__((ext_vector_type(4))) float f32x4;
typedef __attribute__((ext_vector_type(4))) unsigned int u32x4;

#define NB 2
#define NQ 1024
#define PAST 1024
#define MAXC 4096
#define NH 32
#define NKV 8
#define HD 128
#define HID 4096
#define SEQK 2048          // PAST + NQ
#define QKV_N 6144         // (H + 2*HKV) * D
#define SCALE 0.08838834764831845f
#define LOG2E 1.4426950408889634f
// q pre-scale folds softmax scale AND log2(e): scores come out in log2 units,
// so attn uses exp2 directly with no per-element multiply.
#define QSCALE (0.08838834764831845f * 1.4426950408889634f)

// async global->LDS, 16 B per lane (wave writes base + lane*16, linear)
__device__ __forceinline__ void async16(const bf16* g, bf16* l) {
    __builtin_amdgcn_global_load_lds(
        (const __attribute__((address_space(1))) void*)g,
        (__attribute__((address_space(3))) void*)l, 16, 0, 0);
}

// ---------------------------------------------------------------------------
// QKV GEMM: 256x192 tile, BK=64, 8 waves (2Mx4N), double-buffered LDS with
// issue-early staging.  Grid = 8x32 = 256 blocks -> exactly 1 block per CU.
// Source-pre-swizzled global_load_lds staging (zero bank conflicts).
// Column-major XCD chunking: each XCD owns 4 B-panels (6 MB) + A sweep.
// ---------------------------------------------------------------------------
__global__ __launch_bounds__(512, 2) void gemm_qkv(const bf16* __restrict__ A,
                                                   const bf16* __restrict__ Bt,
                                                   bf16* __restrict__ C,
                                                   int N, int K) {
    __shared__ bf16 As[2][256 * 64];
    __shared__ bf16 Bs[2][192 * 64];
    const int orig = blockIdx.x;                       // 256 blocks
    const int wg   = (orig & 7) * 32 + (orig >> 3);    // cluster per XCD
    const int by   = wg & 7, bx = wg >> 3;             // column-major sweep
    const int rowBase = by * 256, colBase = bx * 192;

    const int tid  = threadIdx.x;
    const int lane = tid & 63;
    const int wv   = tid >> 6;                 // 0..7
    const int wm   = wv >> 2, wn = wv & 3;     // wave grid 2x4
    const int l15  = lane & 15, quad = lane >> 4;

    // staging source: lane covers row sr (of an 8-row chunk), swizzled col
    const int sr = lane >> 3;                  // 0..7
    const int sc = ((lane & 7) ^ sr) * 8;      // pre-swizzled col (elements)
    const bf16* aG = A  + (long)(rowBase + wv * 32 + sr) * K + sc;  // 4x8 rows
    const bf16* bG = Bt + (long)(colBase + wv * 24 + sr) * K + sc;  // 3x8 rows

    f32x4 acc[8][3];
#pragma unroll
    for (int i = 0; i < 8; i++)
#pragma unroll
        for (int j = 0; j < 3; j++) acc[i][j] = (f32x4){0.f, 0.f, 0.f, 0.f};

    const int nt = K >> 6;
    // prologue: stage tile 0 into buf 0
#pragma unroll
    for (int j = 0; j < 4; j++)
        async16(aG + (long)(j * 8) * K, &As[0][(wv * 32 + j * 8) * 64]);
#pragma unroll
    for (int j = 0; j < 3; j++)
        async16(bG + (long)(j * 8) * K, &Bs[0][(wv * 24 + j * 8) * 64]);
    __syncthreads();

    for (int t = 0; t < nt; t++) {
        const int cur = t & 1;
        if (t + 1 < nt) {                      // issue-early: stage t+1 now
            const int kn = (t + 1) << 6;
#pragma unroll
            for (int j = 0; j < 4; j++)
                async16(aG + (long)(j * 8) * K + kn, &As[cur ^ 1][(wv * 32 + j * 8) * 64]);
#pragma unroll
            for (int j = 0; j < 3; j++)
                async16(bG + (long)(j * 8) * K + kn, &Bs[cur ^ 1][(wv * 24 + j * 8) * 64]);
        }
#pragma unroll
        for (int kc = 0; kc < 2; kc++) {
            bf16x8 af[8], bfr[3];
#pragma unroll
            for (int mi = 0; mi < 8; mi++)
                af[mi] = *(const bf16x8*)&As[cur][(wm * 128 + mi * 16 + l15) * 64 +
                                                  ((kc * 32 + quad * 8) ^ ((l15 & 7) * 8))];
#pragma unroll
            for (int ni = 0; ni < 3; ni++)
                bfr[ni] = *(const bf16x8*)&Bs[cur][(wn * 48 + ni * 16 + l15) * 64 +
                                                   ((kc * 32 + quad * 8) ^ ((l15 & 7) * 8))];
            __builtin_amdgcn_s_setprio(1);
#pragma unroll
            for (int mi = 0; mi < 8; mi++)
#pragma unroll
                for (int ni = 0; ni < 3; ni++)
                    acc[mi][ni] = __builtin_amdgcn_mfma_f32_16x16x32_bf16(
                        af[mi], bfr[ni], acc[mi][ni], 0, 0, 0);
            __builtin_amdgcn_s_setprio(0);
        }
        __syncthreads();                       // drains vmcnt (t+1 loads landed)
    }
    // C/D layout: col = lane&15, row = quad*4 + reg  (m89-verified)
#pragma unroll
    for (int mi = 0; mi < 8; mi++)
#pragma unroll
        for (int r = 0; r < 4; r++) {
            const int row = rowBase + wm * 128 + mi * 16 + quad * 4 + r;
#pragma unroll
            for (int ni = 0; ni < 3; ni++) {
                const int col = colBase + wn * 48 + ni * 16 + l15;
                C[(long)row * N + col] = (bf16)acc[mi][ni][r];
            }
        }
}

// ---------------------------------------------------------------------------
// 128x128-tile GEMM (o-proj): dbuf issue-early, BK=64, 4 waves (2x2),
// 64 KB LDS -> 2 blocks/CU.
// ---------------------------------------------------------------------------
template <bool F32OUT>
__global__ __launch_bounds__(256) void gemm_bb(const bf16* __restrict__ A,
                                               const bf16* __restrict__ Bt,
                                               void* __restrict__ Cv,
                                               int M, int N, int K, int nbx) {
    __shared__ bf16 As[2][128 * 64];
    __shared__ bf16 Bs[2][128 * 64];
    const int nwg  = gridDim.x;
    const int cpx  = nwg >> 3;
    const int orig = blockIdx.x;
    const int wg   = (orig & 7) * cpx + (orig >> 3);
    const int by = wg / nbx, bx = wg - by * nbx;
    const int rowBase = by * 128, colBase = bx * 128;

    const int tid  = threadIdx.x;
    const int lane = tid & 63;
    const int wv   = tid >> 6;
    const int wm   = wv >> 1, wn = wv & 1;
    const int l15  = lane & 15, quad = lane >> 4;

    const int sr = lane >> 3;
    const int sc = ((lane & 7) ^ sr) * 8;
    const bf16* aG = A  + (long)(rowBase + wv * 32 + sr) * K + sc;
    const bf16* bG = Bt + (long)(colBase + wv * 32 + sr) * K + sc;

    f32x4 acc[4][4];
#pragma unroll
    for (int i = 0; i < 4; i++)
#pragma unroll
        for (int j = 0; j < 4; j++) acc[i][j] = (f32x4){0.f, 0.f, 0.f, 0.f};

    const int nt = K >> 6;
#pragma unroll
    for (int j = 0; j < 4; j++) {
        async16(aG + (long)(j * 8) * K, &As[0][(wv * 32 + j * 8) * 64]);
        async16(bG + (long)(j * 8) * K, &Bs[0][(wv * 32 + j * 8) * 64]);
    }
    __syncthreads();

    for (int t = 0; t < nt; t++) {
        const int cur = t & 1;
        if (t + 1 < nt) {
            const int kn = (t + 1) << 6;
#pragma unroll
            for (int j = 0; j < 4; j++) {
                async16(aG + (long)(j * 8) * K + kn, &As[cur ^ 1][(wv * 32 + j * 8) * 64]);
                async16(bG + (long)(j * 8) * K + kn, &Bs[cur ^ 1][(wv * 32 + j * 8) * 64]);
            }
        }
#pragma unroll
        for (int kc = 0; kc < 2; kc++) {
            bf16x8 af[4], bfr[4];
#pragma unroll
            for (int mi = 0; mi < 4; mi++)
                af[mi] = *(const bf16x8*)&As[cur][(wm * 64 + mi * 16 + l15) * 64 +
                                                  ((kc * 32 + quad * 8) ^ ((l15 & 7) * 8))];
#pragma unroll
            for (int ni = 0; ni < 4; ni++)
                bfr[ni] = *(const bf16x8*)&Bs[cur][(wn * 64 + ni * 16 + l15) * 64 +
                                                   ((kc * 32 + quad * 8) ^ ((l15 & 7) * 8))];
            __builtin_amdgcn_s_setprio(1);
#pragma unroll
            for (int mi = 0; mi < 4; mi++)
#pragma unroll
                for (int ni = 0; ni < 4; ni++)
                    acc[mi][ni] = __builtin_amdgcn_mfma_f32_16x16x32_bf16(
                        af[mi], bfr[ni], acc[mi][ni], 0, 0, 0);
            __builtin_amdgcn_s_setprio(0);
        }
        __syncthreads();
    }
#pragma unroll
    for (int mi = 0; mi < 4; mi++)
#pragma unroll
        for (int r = 0; r < 4; r++) {
            const int row = rowBase + wm * 64 + mi * 16 + quad * 4 + r;
#pragma unroll
            for (int ni = 0; ni < 4; ni++) {
                const int col = colBase + wn * 64 + ni * 16 + l15;
                if (F32OUT) ((float*)Cv)[(long)row * N + col] = acc[mi][ni][r];
                else        ((bf16*)Cv)[(long)row * N + col] = (bf16)acc[mi][ni][r];
            }
        }
}

// ---------------------------------------------------------------------------
// fp32 -> bf16 convert (vectorized, 8 elems/thread)
// ---------------------------------------------------------------------------
__global__ void conv_f2b(const float* __restrict__ in, bf16* __restrict__ out) {
    const long e = ((long)blockIdx.x * 256 + threadIdx.x) * 8;
    const f32x4 a = *(const f32x4*)&in[e];
    const f32x4 b = *(const f32x4*)&in[e + 4];
    bf16x8 v;
#pragma unroll
    for (int j = 0; j < 4; j++) { v[j] = (bf16)a[j]; v[4 + j] = (bf16)b[j]; }
    *(bf16x8*)&out[e] = v;
}

// ---------------------------------------------------------------------------
// Transpose + convert: out(C,R) bf16 = in(R,C) fp32 transposed.
// ---------------------------------------------------------------------------
__global__ __launch_bounds__(256) void transpose_f2b(const float* __restrict__ in,
                                                     bf16* __restrict__ out,
                                                     int R, int C) {
    __shared__ bf16 t[64][72];
    const int r0 = blockIdx.y * 64, c0 = blockIdx.x * 64;
    const int tid = threadIdx.x;
    const int lr = tid >> 3;          // 0..31
    const int lc = (tid & 7) * 8;     // 0..56
#pragma unroll
    for (int i = 0; i < 2; i++) {
        const f32x4* p = (const f32x4*)&in[(long)(r0 + lr + i * 32) * C + c0 + lc];
        const f32x4 v0 = p[0], v1 = p[1];
        bf16x8 v;
#pragma unroll
        for (int j = 0; j < 4; j++) { v[j] = (bf16)v0[j]; v[4 + j] = (bf16)v1[j]; }
        *(bf16x8*)&t[lr + i * 32][lc] = v;
    }
    __syncthreads();
#pragma unroll
    for (int i = 0; i < 2; i++) {
        const int oc = lr + i * 32;
        bf16x8 v;
#pragma unroll
        for (int j = 0; j < 8; j++) v[j] = t[lc + j][oc];
        *(bf16x8*)&out[(long)(c0 + oc) * R + r0 + lc] = v;
    }
}

// ---------------------------------------------------------------------------
// Batched bf16->bf16 transpose (used for V-present -> V^T).
// ---------------------------------------------------------------------------
__global__ __launch_bounds__(256) void transpose_bf16(const bf16* __restrict__ in,
                                                      bf16* __restrict__ out,
                                                      int R, int C,
                                                      long inBS, long outBS) {
    __shared__ bf16 t[64][72];
    in  += (long)blockIdx.z * inBS;
    out += (long)blockIdx.z * outBS;
    const int r0 = blockIdx.y * 64, c0 = blockIdx.x * 64;
    const int tid = threadIdx.x;
    const int lr = tid >> 3;
    const int lc = (tid & 7) * 8;
#pragma unroll
    for (int i = 0; i < 2; i++)
        *(u32x4*)&t[lr + i * 32][lc] =
            *(const u32x4*)&in[(long)(r0 + lr + i * 32) * C + c0 + lc];
    __syncthreads();
#pragma unroll
    for (int i = 0; i < 2; i++) {
        const int oc = lr + i * 32;
        bf16x8 v;
#pragma unroll
        for (int j = 0; j < 8; j++) v[j] = t[lc + j][oc];
        *(bf16x8*)&out[(long)(c0 + oc) * R + r0 + lc] = v;
    }
}

// ---------------------------------------------------------------------------
// Fused cache copy: fp32 caches -> d_out (all 4096 rows) AND first-2048-row
// compact bf16 conversion.  grid (256, 16, 2) x 256.
// ---------------------------------------------------------------------------
__global__ void cache_copy(const float* __restrict__ kc, const float* __restrict__ vc,
                           float* __restrict__ ok, float* __restrict__ ov,
                           bf16* __restrict__ kb, bf16* __restrict__ vb) {
    const int bh = blockIdx.y;
    const long idx = ((long)blockIdx.x * 256 + threadIdx.x) * 8;  // < MAXC*HD
    const float* src = (blockIdx.z ? vc : kc) + (long)bh * MAXC * HD + idx;
    float* dst = (blockIdx.z ? ov : ok) + (long)bh * MAXC * HD + idx;
    const f32x4 a = *(const f32x4*)src;
    const f32x4 c = *(const f32x4*)(src + 4);
    *(f32x4*)dst = a;
    *(f32x4*)(dst + 4) = c;
    if (idx < (long)SEQK * HD) {               // compact bf16 (present rows)
        bf16* db = (blockIdx.z ? vb : kb) + (long)bh * SEQK * HD + idx;
        bf16x8 v;
#pragma unroll
        for (int j = 0; j < 4; j++) { v[j] = (bf16)a[j]; v[4 + j] = (bf16)c[j]; }
        *(bf16x8*)db = v;
    }
}

// ---------------------------------------------------------------------------
// Per (b,q): RMSNorm (q,k), RoPE (q,k), scatter — ALL 48 heads per block.
// grid (1024,2) x 256 threads; wave w loops over heads {w, w+4, ..., w+44}.
// ---------------------------------------------------------------------------
__global__ __launch_bounds__(256) void qkv_post(const bf16* __restrict__ qkv,
                                                const float* __restrict__ cs,
                                                const int* __restrict__ kvstart,
                                                const float* __restrict__ qw,
                                                const float* __restrict__ kw,
                                                bf16* __restrict__ qbuf,
                                                float* __restrict__ outk,
                                                float* __restrict__ outv,
                                                bf16* __restrict__ kb,
                                                bf16* __restrict__ vb) {
    const int q = blockIdx.x;
    const int b = blockIdx.y;
    const int l = threadIdx.x & 63;
    const int wv = threadIdx.x >> 6;
    const int pos = kvstart[b] + q;
    const float c = cs[(long)pos * HD + l];
    const float s = cs[(long)pos * HD + 64 + l];
    const float qw1 = qw[l], qw2 = qw[l + 64];
    const float kw1 = kw[l], kw2 = kw[l + 64];
    const bf16* xb = qkv + (long)(b * NQ + q) * QKV_N;

    for (int h = wv; h < 48; h += 4) {         // wave-uniform head loop
        const bf16* x = xb + h * HD;
        float x1 = (float)x[l], x2 = (float)x[l + 64];
        if (h < 40) {
            float sq = x1 * x1 + x2 * x2;
#pragma unroll
            for (int m = 32; m >= 1; m >>= 1) sq += __shfl_xor(sq, m);
            const float rr = rsqrtf(sq * (1.0f / 128.0f) + 1e-6f);
            const float w1 = (h < 32) ? qw1 : kw1;
            const float w2 = (h < 32) ? qw2 : kw2;
            const float y1 = x1 * rr * w1;
            const float y2 = x2 * rr * w2;
            const float o1 = y1 * c - y2 * s;
            const float o2 = y2 * c + y1 * s;
            if (h < 32) {  // fold softmax scale * log2(e) into q
                bf16* dst = qbuf + ((long)(b * NH + h) * NQ + q) * HD;
                dst[l] = (bf16)(o1 * QSCALE);
                dst[l + 64] = (bf16)(o2 * QSCALE);
            } else {
                const int hk = h - 32;
                float* df = outk + ((long)(b * NKV + hk) * MAXC + pos) * HD;
                df[l] = o1; df[l + 64] = o2;
                bf16* db = kb + ((long)(b * NKV + hk) * SEQK + pos) * HD;
                db[l] = (bf16)o1; db[l + 64] = (bf16)o2;
            }
        } else {
            const int hk = h - 40;
            float* df = outv + ((long)(b * NKV + hk) * MAXC + pos) * HD;
            df[l] = x1; df[l + 64] = x2;
            bf16* db = vb + ((long)(b * NKV + hk) * SEQK + pos) * HD;
            db[l] = (bf16)x1; db[l + 64] = (bf16)x2;
        }
    }
}

// ---------------------------------------------------------------------------
// Flash attention v5: occupancy-4x restructure.
// r8 post-mortem: 4650 cy/block-tile measured vs ~1500 cy pipe-sum -> attn is
// STALL-bound at 2 blocks/CU (8 waves, 17.5% occupancy): barrier + L2-latency
// bubbles exposed.  v5 shrinks the block: KVBLK=32, 16 q-rows/wave (ss gone),
// 64 rows/block, grid (16,32,2) = 1024 blocks = 4/CU.
//   LDS = Ks[2][32][128] + Vs[2][128][32] + Ps[4][16][64] = 40 KB -> 4 blk/CU
//   VGPR ~100 (aq16 + o32 + s8 + addr) under the 128 cap of bounds(256,4)
//   -> 16 waves/CU (4/SIMD): 2x the stall-absorbing TLP.
// Same proven machinery: pre-swizzled global_load_lds dbuf staging,
// issue-early, swapped QK^T, defer-max, Ps exchange, XCD-clustered remap.
// ---------------------------------------------------------------------------
__global__ __launch_bounds__(256, 4) void attn_fwd(const bf16* __restrict__ qbuf,
                                                   const bf16* __restrict__ kb,
                                                   const bf16* __restrict__ vt,
                                                   bf16* __restrict__ oheads) {
    // bijective remap of 1024 blocks: xcd = ib&7 owns groups g = xcd*8..+7
    // (2 MB K/V per XCD, L2-resident); qraw pairing balances ntiles.
    const int ib  = blockIdx.x + 16 * (blockIdx.y + 32 * blockIdx.z);
    const int xc  = ib & 7, j = ib >> 3;       // j 0..127
    const int g   = xc * 8 + (j & 7);          // (h,b) group
    const int h   = g & 31, b = g >> 5;
    const int qraw = j >> 3;                   // 0..15
    const int qt  = (qraw < 8) ? qraw : 23 - qraw;  // pair sums = 23
    const int hk  = h >> 2;
    const int tid = threadIdx.x;
    const int lane = tid & 63, wv = tid >> 6;
    const int l15 = lane & 15, quad = lane >> 4;

    __shared__ bf16 Ks[2][32][128];   // [buf][key][d]   swizzled, 16 KB
    __shared__ bf16 Vs[2][128][32];   // [buf][d][key]   swizzled, 16 KB
    __shared__ bf16 Ps[4][16][64];    // per-wave P      swizzled,  8 KB

    const int qb = qt * 64 + wv * 16;          // wave's 16 q-rows

    const bf16* kB = kb + (long)(b * NKV + hk) * SEQK * HD;       // [2048][128]
    const bf16* vB = vt + (long)(b * NKV + hk) * HD * (long)SEQK; // [128][2048]

    // staging geometry (call i covers LDS chunk c = tid + i*256, 16 B each):
    // K: row = tid>>4 + i*16, chunk = tid&15, src-chunk ^= row&7
    // V: row = tid>>2 + i*64, chunk = tid&3,  src-chunk ^= row&3
    const int kRow = tid >> 4;
    const int kCol = ((tid & 15) ^ (kRow & 7)) * 8;
    const int vRow = tid >> 2;
    const int vCol = ((tid & 3) ^ (vRow & 3)) * 8;

    bf16x8 aq[4];
    {
        const bf16* qp = qbuf + ((long)(b * NH + h) * NQ + qb + l15) * HD + quad * 8;
#pragma unroll
        for (int kc = 0; kc < 4; kc++) aq[kc] = *(const bf16x8*)(qp + kc * 32);
    }

    f32x4 o[8];
#pragma unroll
    for (int dt = 0; dt < 8; dt++) o[dt] = (f32x4){0.f, 0.f, 0.f, 0.f};
    float m_ = -1e30f, l_ = 0.f;

    const int ntiles = (qt * 64 + 63 + PAST + 32) >> 5;   // block-wide cover
    const int wlast  = qb + 15 + PAST;                    // wave's last key

    // prologue: stage tile 0 into buf 0
#pragma unroll
    for (int i = 0; i < 2; i++) {
        async16(kB + (long)(kRow + i * 16) * HD + kCol,
                &Ks[0][0][0] + wv * 512 + i * 2048);
        async16(vB + (long)(vRow + i * 64) * SEQK + vCol,
                &Vs[0][0][0] + wv * 512 + i * 2048);
    }
    __syncthreads();

    for (int t = 0; t < ntiles; t++) {
        const int cur = t & 1;
        const int k0 = t * 32;
        if (t + 1 < ntiles) {                  // issue-early: stage t+1 now
            const int kn = k0 + 32;
#pragma unroll
            for (int i = 0; i < 2; i++) {
                async16(kB + (long)(kn + kRow + i * 16) * HD + kCol,
                        &Ks[cur ^ 1][0][0] + wv * 512 + i * 2048);
                async16(vB + (long)(vRow + i * 64) * SEQK + kn + vCol,
                        &Vs[cur ^ 1][0][0] + wv * 512 + i * 2048);
            }
        }

        if (k0 <= wlast) {                     // wave-uniform compute guard
            // ---- QK^T (swapped): S^T, row = key, col = q ----
            f32x4 s[2];
            s[0] = (f32x4){0.f, 0.f, 0.f, 0.f};
            s[1] = (f32x4){0.f, 0.f, 0.f, 0.f};
            __builtin_amdgcn_s_setprio(1);
#pragma unroll
            for (int kc = 0; kc < 4; kc++) {
                const bf16x8 bk0 = *(const bf16x8*)
                    &Ks[cur][l15][(kc * 32 + quad * 8) ^ ((l15 & 7) * 8)];
                const bf16x8 bk1 = *(const bf16x8*)
                    &Ks[cur][16 + l15][(kc * 32 + quad * 8) ^ ((l15 & 7) * 8)];
                s[0] = __builtin_amdgcn_mfma_f32_16x16x32_bf16(bk0, aq[kc], s[0], 0, 0, 0);
                s[1] = __builtin_amdgcn_mfma_f32_16x16x32_bf16(bk1, aq[kc], s[1], 0, 0, 0);
            }
            __builtin_amdgcn_s_setprio(0);

            // ---- causal mask (boundary tiles only) ----
            if (k0 + 31 > qb + PAST) {
                const int lim = qb + l15 + PAST - k0;   // max allowed rel key
#pragma unroll
                for (int nk = 0; nk < 2; nk++)
#pragma unroll
                    for (int r = 0; r < 4; r++)
                        if (nk * 16 + quad * 4 + r > lim) s[nk][r] = -1e30f;
            }
            // ---- online softmax (lane owns q-row qb+l15; 8 keys in-lane,
            //      row spread over 4 quad-replicas -> 2 shfls) ----
            float mx = s[0][0];
#pragma unroll
            for (int nk = 0; nk < 2; nk++)
#pragma unroll
                for (int r = 0; r < 4; r++) mx = fmaxf(mx, s[nk][r]);
            mx = fmaxf(mx, __shfl_xor(mx, 16));
            mx = fmaxf(mx, __shfl_xor(mx, 32));
            // T13 defer-max: rescale only when some row's max grew > 8
            if (!__all(mx - m_ <= 8.f)) {
                const float mn = fmaxf(m_, mx);
                const float alpha = exp2f(m_ - mn);
                m_ = mn;
                l_ *= alpha;
#pragma unroll
                for (int r = 0; r < 4; r++) {
                    const float ar = __shfl(alpha, (lane & 48) + quad * 4 + r);
#pragma unroll
                    for (int dt = 0; dt < 8; dt++) o[dt][r] *= ar;
                }
            }
            float sum = 0.f;
#pragma unroll
            for (int nk = 0; nk < 2; nk++)
#pragma unroll
                for (int r = 0; r < 4; r++) {
                    const float p = exp2f(s[nk][r] - m_);
                    s[nk][r] = p;
                    sum += p;
                }
            sum += __shfl_xor(sum, 16);
            sum += __shfl_xor(sum, 32);
            l_ += sum;
            // P-store: 4 consecutive keys per lane -> packed b64 writes
#pragma unroll
            for (int nk = 0; nk < 2; nk++) {
                bf16x4 pv;
#pragma unroll
                for (int r = 0; r < 4; r++) pv[r] = (bf16)s[nk][r];
                *(bf16x4*)&Ps[wv][l15][(nk * 16 + quad * 4) ^ ((l15 & 7) * 8)] = pv;
            }

            // ---- PV: P (A-op) x V^T (B-op), 32 keys = 1 k-chunk ----
            __builtin_amdgcn_s_setprio(1);
            const bf16x8 ap = *(const bf16x8*)
                &Ps[wv][l15][(quad * 8) ^ ((l15 & 7) * 8)];
#pragma unroll
            for (int dt = 0; dt < 8; dt++) {
                const bf16x8 bv = *(const bf16x8*)
                    &Vs[cur][dt * 16 + l15][(quad ^ (l15 & 3)) * 8];
                o[dt] = __builtin_amdgcn_mfma_f32_16x16x32_bf16(ap, bv, o[dt], 0, 0, 0);
            }
            __builtin_amdgcn_s_setprio(0);
        }
        __syncthreads();                       // drains staging loads for t+1
    }

    float inv[4];
#pragma unroll
    for (int r = 0; r < 4; r++) {
        const float lr = __shfl(l_, (lane & 48) + quad * 4 + r);
        inv[r] = 1.0f / lr;
    }
#pragma unroll
    for (int dt = 0; dt < 8; dt++)
#pragma unroll
        for (int r = 0; r < 4; r++) {
            const int row = qb + quad * 4 + r;
            oheads[((long)(b * NH + h) * NQ + row) * HD + dt * 16 + l15] =
                (bf16)(o[dt][r] * inv[r]);
        }
}

// ---------------------------------------------------------------------------
// sum over GQA groups: oheads (B,NH,Q,D) bf16 -> osum (B,Q,HKV*D) bf16
// ---------------------------------------------------------------------------
__global__ void group_sum(const bf16* __restrict__ oheads, bf16* __restrict__ osum) {
    const long e = ((long)blockIdx.x * 256 + threadIdx.x) * 8;
    const int b = (int)(e >> 20);
    const int rem = (int)(e & 1048575);
    const int q = rem >> 10;
    const int col = rem & 1023;
    const int hk = col >> 7;
    const int d = col & 127;
    float acc[8] = {0.f, 0.f, 0.f, 0.f, 0.f, 0.f, 0.f, 0.f};
#pragma unroll
    for (int g = 0; g < 4; g++) {
        const bf16x8 v = *(const bf16x8*)
            &oheads[((long)(b * NH + hk * 4 + g) * NQ + q) * HD + d];
#pragma unroll
        for (int j = 0; j < 8; j++) acc[j] += (float)v[j];
    }
    bf16x8 r;
#pragma unroll
    for (int j = 0; j < 8; j++) r[j] = (bf16)acc[j];
    *(bf16x8*)&osum[e] = r;
}

// ---------------------------------------------------------------------------
extern "C" void kernel_launch(void* const* d_in, const int* in_sizes, int n_in,
                              void* d_out, int out_size, void* d_ws, size_t ws_size,
                              hipStream_t stream) {
    const float* hidden  = (const float*)d_in[0];
    const float* kc_in   = (const float*)d_in[1];
    const float* vc_in   = (const float*)d_in[2];
    const float* rope_cs = (const float*)d_in[3];
    const int*   kvstart = (const int*)d_in[5];
    const float* w_qkv   = (const float*)d_in[6];
    const float* w_o     = (const float*)d_in[7];
    const float* qnw     = (const float*)d_in[8];
    const float* knw     = (const float*)d_in[9];

    float* out_attn = (float*)d_out;            // 8,388,608 f32
    float* out_k    = out_attn + 8388608L;      // 8,388,608 f32
    float* out_v    = out_k + 8388608L;         // 8,388,608 f32

    // d_out scratch (all regions rewritten before their real contents land):
    char* ob = (char*)d_out;
    bf16* qbuf  = (bf16*)ob;                    // 16,777,216 B ) together exactly
    bf16* kb16  = (bf16*)(ob + 16777216);       //  8,388,608 B ) fill the attn
    bf16* vtb16 = (bf16*)(ob + 25165824);       //  8,388,608 B ) region (33.5MB)
    bf16* wqkvT = (bf16*)(ob + 33554432);       // 50,331,648 B, dead before cache_copy
    bf16* hb16  = (bf16*)(ob + 83886080);       // 16,777,216 B, dead before cache_copy

    char* ws = (char*)d_ws;                     // total use: 32 MiB
    bf16*  qkvb   = (bf16*)ws;                  // 25,165,824 B
    bf16*  vpb16  = (bf16*)(ws + 25165824);     //  8,388,608 B
    bf16*  oheads = (bf16*)ws;                  // 16,777,216 B (qkvb dead)
    bf16*  osum   = (bf16*)(ws + 16777216);     //  4,194,304 B (qkvb dead)
    bf16*  woT    = (bf16*)(ws + 25165824);     //  8,388,608 B (vpb16 dead)

    // 1. hidden (2048,4096) f32 -> bf16  [d_out scratch, dead before cache_copy]
    conv_f2b<<<dim3(4096), 256, 0, stream>>>(hidden, hb16);
    // 2. w_qkv (4096,6144) f32 -> wqkvT (6144,4096) bf16   [d_out scratch]
    transpose_f2b<<<dim3(96, 64), 256, 0, stream>>>(w_qkv, wqkvT, HID, QKV_N);
    // 3. qkv = hidden @ w_qkv (bf16 out); 256 blocks (8 x 32 tiles of 256x192)
    gemm_qkv<<<dim3(256), 512, 0, stream>>>(hb16, wqkvT, qkvb, QKV_N, HID);
    // 4. fused cache copy (fp32, 4096 rows -> d_out) + bf16 compact (2048 rows)
    cache_copy<<<dim3(256, 16, 2), 256, 0, stream>>>(kc_in, vc_in, out_k, out_v,
                                                     kb16, vpb16);
    // 5. rmsnorm + rope + scatter (2048 blocks x 256; 48 heads per block)
    qkv_post<<<dim3(NQ, NB), 256, 0, stream>>>(qkvb, rope_cs, kvstart, qnw, knw,
                                               qbuf, out_k, out_v, kb16, vpb16);
    // 6. V present (2048,128) -> V^T (128,2048) per (b,hk)
    transpose_bf16<<<dim3(2, 32, 16), 256, 0, stream>>>(vpb16, vtb16, SEQK, HD,
                                                        (long)SEQK * HD, (long)SEQK * HD);
    // 7. flash attention v5 (KVBLK=32, 4 blocks/CU) -> per-head O (bf16)
    attn_fwd<<<dim3(16, NH, NB), 256, 0, stream>>>(qbuf, kb16, vtb16, oheads);
    // 8. sum over GQA groups -> (B,Q,1024) bf16
    group_sum<<<dim3(1024), 256, 0, stream>>>(oheads, osum);
    // 9. w_o (1024,4096) f32 -> woT (4096,1024) bf16
    transpose_f2b<<<dim3(64, 16), 256, 0, stream>>>(w_o, woT, 1024, HID);
    // 10. attn_output = osum @ w_o -> d_out (fp32); 512 blocks (16 x 32)
    gemm_bb<true><<<dim3(512), 256, 0, stream>>>(osum, woT, out_attn, 2048, HID, 1024, 32);
}

// Round 10
// 489.615 us; speedup vs baseline: 1.0334x; 1.0334x over previous
//
#include <hip/hip_runtime.h>

// ---------------------------------------------------------------------------
// EdgeLLMAttentionTRTNative: fused qkv-proj + rmsnorm + rope + cache update +
// GQA causal attention (group-summed) + o-proj.   I/O is FP32 (per reference);
// compute internally in bf16 MFMA with fp32 accumulation.
//
// Shapes: B=2 Q=1024 PAST=1024 MAXC=4096 H=32 HKV=8 D=128 HID=4096
// d_out (fp32) = [attn (2,1024,4096) | present_k (2,8,4096,128) | present_v]
// ---------------------------------------------------------------------------

typedef __bf16 bf16;
typedef __attribute__((ext_vector_type(8))) __bf16 bf16x8;
typedef __attribute__((ext_vector_type(4))) __bf16 bf16x4;
typedef __attribute__((ext_vector_type(4))) float f32x4;
typedef __attribute__((ext_vector_type(4))) unsigned int u32x4;

#define NB 2
#define NQ 1024
#define PAST 1024
#define MAXC 4096
#define NH 32
#define NKV 8
#define HD 128
#define HID 4096
#define SEQK 2048          // PAST + NQ
#define QKV_N 6144         // (H + 2*HKV) * D
#define SCALE 0.08838834764831845f
#define LOG2E 1.4426950408889634f
// q pre-scale folds softmax scale AND log2(e): scores come out in log2 units,
// so attn uses exp2 directly with no per-element multiply.
#define QSCALE (0.08838834764831845f * 1.4426950408889634f)

// async global->LDS, 16 B per lane (wave writes base + lane*16, linear)
__device__ __forceinline__ void async16(const bf16* g, bf16* l) {
    __builtin_amdgcn_global_load_lds(
        (const __attribute__((address_space(1))) void*)g,
        (__attribute__((address_space(3))) void*)l, 16, 0, 0);
}

// ---------------------------------------------------------------------------
// QKV GEMM: 256x192 tile, BK=64, 8 waves (2Mx4N), double-buffered LDS with
// issue-early staging.  Grid = 8x32 = 256 blocks -> exactly 1 block per CU.
// Source-pre-swizzled global_load_lds staging (zero bank conflicts).
// Column-major XCD chunking: each XCD owns 4 B-panels (6 MB) + A sweep.
// ---------------------------------------------------------------------------
__global__ __launch_bounds__(512, 2) void gemm_qkv(const bf16* __restrict__ A,
                                                   const bf16* __restrict__ Bt,
                                                   bf16* __restrict__ C,
                                                   int N, int K) {
    __shared__ bf16 As[2][256 * 64];
    __shared__ bf16 Bs[2][192 * 64];
    const int orig = blockIdx.x;                       // 256 blocks
    const int wg   = (orig & 7) * 32 + (orig >> 3);    // cluster per XCD
    const int by   = wg & 7, bx = wg >> 3;             // column-major sweep
    const int rowBase = by * 256, colBase = bx * 192;

    const int tid  = threadIdx.x;
    const int lane = tid & 63;
    const int wv   = tid >> 6;                 // 0..7
    const int wm   = wv >> 2, wn = wv & 3;     // wave grid 2x4
    const int l15  = lane & 15, quad = lane >> 4;

    // staging source: lane covers row sr (of an 8-row chunk), swizzled col
    const int sr = lane >> 3;                  // 0..7
    const int sc = ((lane & 7) ^ sr) * 8;      // pre-swizzled col (elements)
    const bf16* aG = A  + (long)(rowBase + wv * 32 + sr) * K + sc;  // 4x8 rows
    const bf16* bG = Bt + (long)(colBase + wv * 24 + sr) * K + sc;  // 3x8 rows

    f32x4 acc[8][3];
#pragma unroll
    for (int i = 0; i < 8; i++)
#pragma unroll
        for (int j = 0; j < 3; j++) acc[i][j] = (f32x4){0.f, 0.f, 0.f, 0.f};

    const int nt = K >> 6;
    // prologue: stage tile 0 into buf 0
#pragma unroll
    for (int j = 0; j < 4; j++)
        async16(aG + (long)(j * 8) * K, &As[0][(wv * 32 + j * 8) * 64]);
#pragma unroll
    for (int j = 0; j < 3; j++)
        async16(bG + (long)(j * 8) * K, &Bs[0][(wv * 24 + j * 8) * 64]);
    __syncthreads();

    for (int t = 0; t < nt; t++) {
        const int cur = t & 1;
        if (t + 1 < nt) {                      // issue-early: stage t+1 now
            const int kn = (t + 1) << 6;
#pragma unroll
            for (int j = 0; j < 4; j++)
                async16(aG + (long)(j * 8) * K + kn, &As[cur ^ 1][(wv * 32 + j * 8) * 64]);
#pragma unroll
            for (int j = 0; j < 3; j++)
                async16(bG + (long)(j * 8) * K + kn, &Bs[cur ^ 1][(wv * 24 + j * 8) * 64]);
        }
#pragma unroll
        for (int kc = 0; kc < 2; kc++) {
            bf16x8 af[8], bfr[3];
#pragma unroll
            for (int mi = 0; mi < 8; mi++)
                af[mi] = *(const bf16x8*)&As[cur][(wm * 128 + mi * 16 + l15) * 64 +
                                                  ((kc * 32 + quad * 8) ^ ((l15 & 7) * 8))];
#pragma unroll
            for (int ni = 0; ni < 3; ni++)
                bfr[ni] = *(const bf16x8*)&Bs[cur][(wn * 48 + ni * 16 + l15) * 64 +
                                                   ((kc * 32 + quad * 8) ^ ((l15 & 7) * 8))];
            __builtin_amdgcn_s_setprio(1);
#pragma unroll
            for (int mi = 0; mi < 8; mi++)
#pragma unroll
                for (int ni = 0; ni < 3; ni++)
                    acc[mi][ni] = __builtin_amdgcn_mfma_f32_16x16x32_bf16(
                        af[mi], bfr[ni], acc[mi][ni], 0, 0, 0);
            __builtin_amdgcn_s_setprio(0);
        }
        __syncthreads();                       // drains vmcnt (t+1 loads landed)
    }
    // C/D layout: col = lane&15, row = quad*4 + reg  (m89-verified)
#pragma unroll
    for (int mi = 0; mi < 8; mi++)
#pragma unroll
        for (int r = 0; r < 4; r++) {
            const int row = rowBase + wm * 128 + mi * 16 + quad * 4 + r;
#pragma unroll
            for (int ni = 0; ni < 3; ni++) {
                const int col = colBase + wn * 48 + ni * 16 + l15;
                C[(long)row * N + col] = (bf16)acc[mi][ni][r];
            }
        }
}

// ---------------------------------------------------------------------------
// 128x128-tile GEMM (o-proj): dbuf issue-early, BK=64, 4 waves (2x2),
// 64 KB LDS -> 2 blocks/CU.
// ---------------------------------------------------------------------------
template <bool F32OUT>
__global__ __launch_bounds__(256) void gemm_bb(const bf16* __restrict__ A,
                                               const bf16* __restrict__ Bt,
                                               void* __restrict__ Cv,
                                               int M, int N, int K, int nbx) {
    __shared__ bf16 As[2][128 * 64];
    __shared__ bf16 Bs[2][128 * 64];
    const int nwg  = gridDim.x;
    const int cpx  = nwg >> 3;
    const int orig = blockIdx.x;
    const int wg   = (orig & 7) * cpx + (orig >> 3);
    const int by = wg / nbx, bx = wg - by * nbx;
    const int rowBase = by * 128, colBase = bx * 128;

    const int tid  = threadIdx.x;
    const int lane = tid & 63;
    const int wv   = tid >> 6;
    const int wm   = wv >> 1, wn = wv & 1;
    const int l15  = lane & 15, quad = lane >> 4;

    const int sr = lane >> 3;
    const int sc = ((lane & 7) ^ sr) * 8;
    const bf16* aG = A  + (long)(rowBase + wv * 32 + sr) * K + sc;
    const bf16* bG = Bt + (long)(colBase + wv * 32 + sr) * K + sc;

    f32x4 acc[4][4];
#pragma unroll
    for (int i = 0; i < 4; i++)
#pragma unroll
        for (int j = 0; j < 4; j++) acc[i][j] = (f32x4){0.f, 0.f, 0.f, 0.f};

    const int nt = K >> 6;
#pragma unroll
    for (int j = 0; j < 4; j++) {
        async16(aG + (long)(j * 8) * K, &As[0][(wv * 32 + j * 8) * 64]);
        async16(bG + (long)(j * 8) * K, &Bs[0][(wv * 32 + j * 8) * 64]);
    }
    __syncthreads();

    for (int t = 0; t < nt; t++) {
        const int cur = t & 1;
        if (t + 1 < nt) {
            const int kn = (t + 1) << 6;
#pragma unroll
            for (int j = 0; j < 4; j++) {
                async16(aG + (long)(j * 8) * K + kn, &As[cur ^ 1][(wv * 32 + j * 8) * 64]);
                async16(bG + (long)(j * 8) * K + kn, &Bs[cur ^ 1][(wv * 32 + j * 8) * 64]);
            }
        }
#pragma unroll
        for (int kc = 0; kc < 2; kc++) {
            bf16x8 af[4], bfr[4];
#pragma unroll
            for (int mi = 0; mi < 4; mi++)
                af[mi] = *(const bf16x8*)&As[cur][(wm * 64 + mi * 16 + l15) * 64 +
                                                  ((kc * 32 + quad * 8) ^ ((l15 & 7) * 8))];
#pragma unroll
            for (int ni = 0; ni < 4; ni++)
                bfr[ni] = *(const bf16x8*)&Bs[cur][(wn * 64 + ni * 16 + l15) * 64 +
                                                   ((kc * 32 + quad * 8) ^ ((l15 & 7) * 8))];
            __builtin_amdgcn_s_setprio(1);
#pragma unroll
            for (int mi = 0; mi < 4; mi++)
#pragma unroll
                for (int ni = 0; ni < 4; ni++)
                    acc[mi][ni] = __builtin_amdgcn_mfma_f32_16x16x32_bf16(
                        af[mi], bfr[ni], acc[mi][ni], 0, 0, 0);
            __builtin_amdgcn_s_setprio(0);
        }
        __syncthreads();
    }
#pragma unroll
    for (int mi = 0; mi < 4; mi++)
#pragma unroll
        for (int r = 0; r < 4; r++) {
            const int row = rowBase + wm * 64 + mi * 16 + quad * 4 + r;
#pragma unroll
            for (int ni = 0; ni < 4; ni++) {
                const int col = colBase + wn * 64 + ni * 16 + l15;
                if (F32OUT) ((float*)Cv)[(long)row * N + col] = acc[mi][ni][r];
                else        ((bf16*)Cv)[(long)row * N + col] = (bf16)acc[mi][ni][r];
            }
        }
}

// ---------------------------------------------------------------------------
// Transpose + convert: out(C,R) bf16 = in(R,C) fp32 transposed.
// (still used standalone for w_o after vpb16 dies)
// ---------------------------------------------------------------------------
__global__ __launch_bounds__(256) void transpose_f2b(const float* __restrict__ in,
                                                     bf16* __restrict__ out,
                                                     int R, int C) {
    __shared__ bf16 t[64][72];
    const int r0 = blockIdx.y * 64, c0 = blockIdx.x * 64;
    const int tid = threadIdx.x;
    const int lr = tid >> 3;          // 0..31
    const int lc = (tid & 7) * 8;     // 0..56
#pragma unroll
    for (int i = 0; i < 2; i++) {
        const f32x4* p = (const f32x4*)&in[(long)(r0 + lr + i * 32) * C + c0 + lc];
        const f32x4 v0 = p[0], v1 = p[1];
        bf16x8 v;
#pragma unroll
        for (int j = 0; j < 4; j++) { v[j] = (bf16)v0[j]; v[4 + j] = (bf16)v1[j]; }
        *(bf16x8*)&t[lr + i * 32][lc] = v;
    }
    __syncthreads();
#pragma unroll
    for (int i = 0; i < 2; i++) {
        const int oc = lr + i * 32;
        bf16x8 v;
#pragma unroll
        for (int j = 0; j < 8; j++) v[j] = t[lc + j][oc];
        *(bf16x8*)&out[(long)(c0 + oc) * R + r0 + lc] = v;
    }
}

// ---------------------------------------------------------------------------
// Prep kernel: fuses (a) hidden fp32->bf16 convert (blocks 0..4095) and
// (b) w_qkv transpose+convert (blocks 4096..10239).  Independent jobs,
// partitioned by blockIdx (block-uniform branch -> barriers safe).
// r9 accounting: ~7 us/launch boundary -> fuse independent prep work.
// ---------------------------------------------------------------------------
__global__ __launch_bounds__(256) void prep(const float* __restrict__ hidden,
                                            bf16* __restrict__ hb,
                                            const float* __restrict__ wqkv,
                                            bf16* __restrict__ wqkvT) {
    __shared__ bf16 t[64][72];
    const int id = blockIdx.x;
    const int tid = threadIdx.x;
    if (id < 4096) {                       // hidden convert, 8 elems/thread
        const long e = ((long)id * 256 + tid) * 8;
        const f32x4 a = *(const f32x4*)&hidden[e];
        const f32x4 b = *(const f32x4*)&hidden[e + 4];
        bf16x8 v;
#pragma unroll
        for (int j = 0; j < 4; j++) { v[j] = (bf16)a[j]; v[4 + j] = (bf16)b[j]; }
        *(bf16x8*)&hb[e] = v;
    } else {                               // w_qkv (4096,6144) -> (6144,4096)
        const int r = id - 4096;           // 0..6143
        const int bx = r % 96, by = r / 96;
        const int r0 = by * 64, c0 = bx * 64;
        const int lr = tid >> 3;
        const int lc = (tid & 7) * 8;
#pragma unroll
        for (int i = 0; i < 2; i++) {
            const f32x4* p = (const f32x4*)&wqkv[(long)(r0 + lr + i * 32) * QKV_N + c0 + lc];
            const f32x4 v0 = p[0], v1 = p[1];
            bf16x8 v;
#pragma unroll
            for (int j = 0; j < 4; j++) { v[j] = (bf16)v0[j]; v[4 + j] = (bf16)v1[j]; }
            *(bf16x8*)&t[lr + i * 32][lc] = v;
        }
        __syncthreads();
#pragma unroll
        for (int i = 0; i < 2; i++) {
            const int oc = lr + i * 32;
            bf16x8 v;
#pragma unroll
            for (int j = 0; j < 8; j++) v[j] = t[lc + j][oc];
            *(bf16x8*)&wqkvT[(long)(c0 + oc) * HID + r0 + lc] = v;
        }
    }
}

// ---------------------------------------------------------------------------
// Batched bf16->bf16 transpose (used for V-present -> V^T).
// ---------------------------------------------------------------------------
__global__ __launch_bounds__(256) void transpose_bf16(const bf16* __restrict__ in,
                                                      bf16* __restrict__ out,
                                                      int R, int C,
                                                      long inBS, long outBS) {
    __shared__ bf16 t[64][72];
    in  += (long)blockIdx.z * inBS;
    out += (long)blockIdx.z * outBS;
    const int r0 = blockIdx.y * 64, c0 = blockIdx.x * 64;
    const int tid = threadIdx.x;
    const int lr = tid >> 3;
    const int lc = (tid & 7) * 8;
#pragma unroll
    for (int i = 0; i < 2; i++)
        *(u32x4*)&t[lr + i * 32][lc] =
            *(const u32x4*)&in[(long)(r0 + lr + i * 32) * C + c0 + lc];
    __syncthreads();
#pragma unroll
    for (int i = 0; i < 2; i++) {
        const int oc = lr + i * 32;
        bf16x8 v;
#pragma unroll
        for (int j = 0; j < 8; j++) v[j] = t[lc + j][oc];
        *(bf16x8*)&out[(long)(c0 + oc) * R + r0 + lc] = v;
    }
}

// ---------------------------------------------------------------------------
// post_fused: cache_copy + qkv_post in one launch (r9: ~7us/boundary).
// Race-free by disjoint writes: the cache part SKIPS rows [st, st+NQ) of
// both the fp32 caches and the compact bf16 buffers (st = kvstart[b]);
// the qkv part writes exactly those rows.
//   blocks 0..8191   : cache part  (z = id&1, bh = (id>>1)&15, bx = id>>5)
//   blocks 8192..10239: qkv part   (q = r&1023, b = r>>10)
// ---------------------------------------------------------------------------
__global__ __launch_bounds__(256) void post_fused(
        const float* __restrict__ kc, const float* __restrict__ vc,
        const bf16* __restrict__ qkv, const float* __restrict__ cs,
        const int* __restrict__ kvstart,
        const float* __restrict__ qw, const float* __restrict__ kw,
        bf16* __restrict__ qbuf, float* __restrict__ outk,
        float* __restrict__ outv, bf16* __restrict__ kb,
        bf16* __restrict__ vb) {
    const int id = blockIdx.x;
    const int tid = threadIdx.x;
    if (id < 8192) {
        // ---- cache copy part ----
        const int z  = id & 1;
        const int bh = (id >> 1) & 15;
        const int bx = id >> 5;                          // 0..255
        const int st = kvstart[bh >> 3];
        const long idx = ((long)bx * 256 + tid) * 8;     // < MAXC*HD
        const int row = (int)(idx >> 7);                 // HD = 128
        if (row >= st && row < st + NQ) return;          // qkv part owns these
        const float* src = (z ? vc : kc) + (long)bh * MAXC * HD + idx;
        float* dst = (z ? outv : outk) + (long)bh * MAXC * HD + idx;
        const f32x4 a = *(const f32x4*)src;
        const f32x4 c = *(const f32x4*)(src + 4);
        *(f32x4*)dst = a;
        *(f32x4*)(dst + 4) = c;
        if (row < SEQK) {                                // compact bf16
            bf16* db = (z ? vb : kb) + (long)bh * SEQK * HD + idx;
            bf16x8 v;
#pragma unroll
            for (int j = 0; j < 4; j++) { v[j] = (bf16)a[j]; v[4 + j] = (bf16)c[j]; }
            *(bf16x8*)db = v;
        }
    } else {
        // ---- rmsnorm + rope + scatter part (48 heads per block) ----
        const int r = id - 8192;
        const int q = r & 1023;
        const int b = r >> 10;
        const int l = tid & 63;
        const int wv = tid >> 6;
        const int pos = kvstart[b] + q;
        const float c = cs[(long)pos * HD + l];
        const float s = cs[(long)pos * HD + 64 + l];
        const float qw1 = qw[l], qw2 = qw[l + 64];
        const float kw1 = kw[l], kw2 = kw[l + 64];
        const bf16* xb = qkv + (long)(b * NQ + q) * QKV_N;

        for (int h = wv; h < 48; h += 4) {               // wave-uniform loop
            const bf16* x = xb + h * HD;
            float x1 = (float)x[l], x2 = (float)x[l + 64];
            if (h < 40) {
                float sq = x1 * x1 + x2 * x2;
#pragma unroll
                for (int m = 32; m >= 1; m >>= 1) sq += __shfl_xor(sq, m);
                const float rr = rsqrtf(sq * (1.0f / 128.0f) + 1e-6f);
                const float w1 = (h < 32) ? qw1 : kw1;
                const float w2 = (h < 32) ? qw2 : kw2;
                const float y1 = x1 * rr * w1;
                const float y2 = x2 * rr * w2;
                const float o1 = y1 * c - y2 * s;
                const float o2 = y2 * c + y1 * s;
                if (h < 32) {  // fold softmax scale * log2(e) into q
                    bf16* dst = qbuf + ((long)(b * NH + h) * NQ + q) * HD;
                    dst[l] = (bf16)(o1 * QSCALE);
                    dst[l + 64] = (bf16)(o2 * QSCALE);
                } else {
                    const int hk = h - 32;
                    float* df = outk + ((long)(b * NKV + hk) * MAXC + pos) * HD;
                    df[l] = o1; df[l + 64] = o2;
                    bf16* db = kb + ((long)(b * NKV + hk) * SEQK + pos) * HD;
                    db[l] = (bf16)o1; db[l + 64] = (bf16)o2;
                }
            } else {
                const int hk = h - 40;
                float* df = outv + ((long)(b * NKV + hk) * MAXC + pos) * HD;
                df[l] = x1; df[l + 64] = x2;
                bf16* db = vb + ((long)(b * NKV + hk) * SEQK + pos) * HD;
                db[l] = (bf16)x1; db[l + 64] = (bf16)x2;
            }
        }
    }
}

// ---------------------------------------------------------------------------
// Flash attention v4 (r8 version, reverted from the v5 regression):
// pipelined global_load_lds K/V staging (dbuf, issue-early), fused-ss LDS
// reads, swapped QK^T, defer-max, Ps-only LDS exchange.  KVBLK=64, 128 q-rows
// per block, 2 blocks/CU.  (r9's KVBLK=32/4-blk variant raised occupancy to
// 35% but tripled bank conflicts and doubled per-tile softmax/barrier
// overhead: 113 vs 101 us -> reverted.)
// ---------------------------------------------------------------------------
__global__ __launch_bounds__(256, 2) void attn_fwd(const bf16* __restrict__ qbuf,
                                                   const bf16* __restrict__ kb,
                                                   const bf16* __restrict__ vt,
                                                   bf16* __restrict__ oheads) {
    // bijective remap of 512 blocks: xcd = id&7 gets groups g = xcd*8..+7
    const int ib  = blockIdx.x + 8 * (blockIdx.y + 32 * blockIdx.z);
    const int xc  = ib & 7, j = ib >> 3;
    const int g   = xc * 8 + (j & 7);      // (h,b) group, clustered per XCD
    const int h   = g & 31, b = g >> 5;
    const int qraw = j >> 3;
    const int qt  = (qraw < 4) ? qraw : 11 - qraw;  // pair sums = 7
    const int hk  = h >> 2;                // GQA: 4 query heads per kv head
    const int tid = threadIdx.x;
    const int lane = tid & 63, wv = tid >> 6;
    const int l15 = lane & 15, quad = lane >> 4;

    __shared__ bf16 Ks[2][64][128];   // [buf][key][d]   swizzled, 32 KB
    __shared__ bf16 Vs[2][128][64];   // [buf][d][key]   swizzled, 32 KB
    __shared__ bf16 Ps[4][32][64];    // per-wave P      swizzled, 16 KB

    const int qb = qt * 128 + wv * 32;

    const bf16* kB = kb + (long)(b * NKV + hk) * SEQK * HD;       // [2048][128]
    const bf16* vB = vt + (long)(b * NKV + hk) * HD * (long)SEQK; // [128][2048]

    // staging geometry: call i covers LDS chunk c = tid + i*256 (16B each).
    const int kRow = tid >> 4;                           // 0..15
    const int kCol = ((tid & 15) ^ (kRow & 7)) * 8;      // pre-swizzled elems
    const int vRow = tid >> 3;                           // 0..31
    const int vCol = ((tid & 7) ^ (vRow & 7)) * 8;

    bf16x8 aq[2][4];
#pragma unroll
    for (int ss = 0; ss < 2; ss++) {
        const bf16* qp = qbuf + ((long)(b * NH + h) * NQ + qb + ss * 16 + l15) * HD + quad * 8;
#pragma unroll
        for (int kc = 0; kc < 4; kc++) aq[ss][kc] = *(const bf16x8*)(qp + kc * 32);
    }

    f32x4 o[2][8];
    float m_[2], l_[2];
#pragma unroll
    for (int ss = 0; ss < 2; ss++) {
#pragma unroll
        for (int dt = 0; dt < 8; dt++) o[ss][dt] = (f32x4){0.f, 0.f, 0.f, 0.f};
        m_[ss] = -1e30f; l_[ss] = 0.f;
    }

    const int ntiles = (qt * 128 + 127 + PAST + 64) >> 6;   // block-wide cover
    const int wlast  = qb + 31 + PAST;                      // wave's last key

    // prologue: stage tile 0 into buf 0
#pragma unroll
    for (int i = 0; i < 4; i++) {
        async16(kB + (long)(kRow + i * 16) * HD + kCol,
                &Ks[0][0][0] + wv * 512 + i * 2048);
        async16(vB + (long)(vRow + i * 32) * SEQK + vCol,
                &Vs[0][0][0] + wv * 512 + i * 2048);
    }
    __syncthreads();

    for (int t = 0; t < ntiles; t++) {
        const int cur = t & 1;
        const int k0 = t * 64;
        if (t + 1 < ntiles) {                  // issue-early: stage t+1 now
            const int kn = k0 + 64;
#pragma unroll
            for (int i = 0; i < 4; i++) {
                async16(kB + (long)(kn + kRow + i * 16) * HD + kCol,
                        &Ks[cur ^ 1][0][0] + wv * 512 + i * 2048);
                async16(vB + (long)(vRow + i * 32) * SEQK + kn + vCol,
                        &Vs[cur ^ 1][0][0] + wv * 512 + i * 2048);
            }
        }

        if (k0 <= wlast) {                     // wave-uniform compute guard
            // ---- QK^T: K fragments read ONCE from LDS, feed both strips ----
            f32x4 s[2][4];
#pragma unroll
            for (int nk = 0; nk < 4; nk++) {
                s[0][nk] = (f32x4){0.f, 0.f, 0.f, 0.f};
                s[1][nk] = (f32x4){0.f, 0.f, 0.f, 0.f};
            }
            __builtin_amdgcn_s_setprio(1);
#pragma unroll
            for (int kc = 0; kc < 4; kc++) {
                bf16x8 bk[4];
#pragma unroll
                for (int nk = 0; nk < 4; nk++)
                    bk[nk] = *(const bf16x8*)
                        &Ks[cur][nk * 16 + l15][(kc * 32 + quad * 8) ^ ((l15 & 7) * 8)];
#pragma unroll
                for (int nk = 0; nk < 4; nk++) {
                    // SWAPPED operands: C = S^T, row = key (quad*4+r), col = q (l15)
                    s[0][nk] = __builtin_amdgcn_mfma_f32_16x16x32_bf16(bk[nk], aq[0][kc], s[0][nk], 0, 0, 0);
                    s[1][nk] = __builtin_amdgcn_mfma_f32_16x16x32_bf16(bk[nk], aq[1][kc], s[1][nk], 0, 0, 0);
                }
            }
            __builtin_amdgcn_s_setprio(0);

            // ---- per-strip: causal mask, online softmax (defer-max), P-store
#pragma unroll
            for (int ss = 0; ss < 2; ss++) {
                const int rbase = qb + ss * 16;
                if (k0 + 63 > rbase + PAST) {
                    const int lim = rbase + l15 + PAST - k0;   // max rel key
#pragma unroll
                    for (int nk = 0; nk < 4; nk++)
#pragma unroll
                        for (int r = 0; r < 4; r++)
                            if (nk * 16 + quad * 4 + r > lim) s[ss][nk][r] = -1e30f;
                }
                float mx = s[ss][0][0];
#pragma unroll
                for (int nk = 0; nk < 4; nk++)
#pragma unroll
                    for (int r = 0; r < 4; r++) mx = fmaxf(mx, s[ss][nk][r]);
                mx = fmaxf(mx, __shfl_xor(mx, 16));
                mx = fmaxf(mx, __shfl_xor(mx, 32));
                // T13 defer-max: rescale only when some row's max grew > 8
                if (!__all(mx - m_[ss] <= 8.f)) {
                    const float mn = fmaxf(m_[ss], mx);
                    const float alpha = exp2f(m_[ss] - mn);
                    m_[ss] = mn;
                    l_[ss] *= alpha;
#pragma unroll
                    for (int r = 0; r < 4; r++) {
                        const float ar = __shfl(alpha, (lane & 48) + quad * 4 + r);
#pragma unroll
                        for (int dt = 0; dt < 8; dt++) o[ss][dt][r] *= ar;
                    }
                }
                float sum = 0.f;
#pragma unroll
                for (int nk = 0; nk < 4; nk++)
#pragma unroll
                    for (int r = 0; r < 4; r++) {
                        const float p = exp2f(s[ss][nk][r] - m_[ss]);
                        s[ss][nk][r] = p;
                        sum += p;
                    }
                sum += __shfl_xor(sum, 16);
                sum += __shfl_xor(sum, 32);
                l_[ss] += sum;
#pragma unroll
                for (int nk = 0; nk < 4; nk++) {
                    bf16x4 pv;
#pragma unroll
                    for (int r = 0; r < 4; r++) pv[r] = (bf16)s[ss][nk][r];
                    *(bf16x4*)&Ps[wv][ss * 16 + l15][(nk * 16 + quad * 4) ^ ((l15 & 7) * 8)] = pv;
                }
            }

            // ---- PV: V fragments read ONCE from LDS, feed both strips ----
            __builtin_amdgcn_s_setprio(1);
#pragma unroll
            for (int kc = 0; kc < 2; kc++) {
                const bf16x8 ap0 = *(const bf16x8*)
                    &Ps[wv][l15][(kc * 32 + quad * 8) ^ ((l15 & 7) * 8)];
                const bf16x8 ap1 = *(const bf16x8*)
                    &Ps[wv][16 + l15][(kc * 32 + quad * 8) ^ ((l15 & 7) * 8)];
#pragma unroll
                for (int dt = 0; dt < 8; dt++) {
                    const bf16x8 bv = *(const bf16x8*)
                        &Vs[cur][dt * 16 + l15][(kc * 32 + quad * 8) ^ ((l15 & 7) * 8)];
                    o[0][dt] = __builtin_amdgcn_mfma_f32_16x16x32_bf16(ap0, bv, o[0][dt], 0, 0, 0);
                    o[1][dt] = __builtin_amdgcn_mfma_f32_16x16x32_bf16(ap1, bv, o[1][dt], 0, 0, 0);
                }
            }
            __builtin_amdgcn_s_setprio(0);
        }
        __syncthreads();                       // drains staging loads for t+1
    }

#pragma unroll
    for (int ss = 0; ss < 2; ss++) {
        float inv[4];
#pragma unroll
        for (int r = 0; r < 4; r++) {
            const float lr = __shfl(l_[ss], (lane & 48) + quad * 4 + r);
            inv[r] = 1.0f / lr;
        }
#pragma unroll
        for (int dt = 0; dt < 8; dt++)
#pragma unroll
            for (int r = 0; r < 4; r++) {
                const int row = qb + ss * 16 + quad * 4 + r;
                oheads[((long)(b * NH + h) * NQ + row) * HD + dt * 16 + l15] =
                    (bf16)(o[ss][dt][r] * inv[r]);
            }
    }
}

// ---------------------------------------------------------------------------
// sum over GQA groups: oheads (B,NH,Q,D) bf16 -> osum (B,Q,HKV*D) bf16
// ---------------------------------------------------------------------------
__global__ void group_sum(const bf16* __restrict__ oheads, bf16* __restrict__ osum) {
    const long e = ((long)blockIdx.x * 256 + threadIdx.x) * 8;
    const int b = (int)(e >> 20);
    const int rem = (int)(e & 1048575);
    const int q = rem >> 10;
    const int col = rem & 1023;
    const int hk = col >> 7;
    const int d = col & 127;
    float acc[8] = {0.f, 0.f, 0.f, 0.f, 0.f, 0.f, 0.f, 0.f};
#pragma unroll
    for (int g = 0; g < 4; g++) {
        const bf16x8 v = *(const bf16x8*)
            &oheads[((long)(b * NH + hk * 4 + g) * NQ + q) * HD + d];
#pragma unroll
        for (int j = 0; j < 8; j++) acc[j] += (float)v[j];
    }
    bf16x8 r;
#pragma unroll
    for (int j = 0; j < 8; j++) r[j] = (bf16)acc[j];
    *(bf16x8*)&osum[e] = r;
}

// ---------------------------------------------------------------------------
extern "C" void kernel_launch(void* const* d_in, const int* in_sizes, int n_in,
                              void* d_out, int out_size, void* d_ws, size_t ws_size,
                              hipStream_t stream) {
    const float* hidden  = (const float*)d_in[0];
    const float* kc_in   = (const float*)d_in[1];
    const float* vc_in   = (const float*)d_in[2];
    const float* rope_cs = (const float*)d_in[3];
    const int*   kvstart = (const int*)d_in[5];
    const float* w_qkv   = (const float*)d_in[6];
    const float* w_o     = (const float*)d_in[7];
    const float* qnw     = (const float*)d_in[8];
    const float* knw     = (const float*)d_in[9];

    float* out_attn = (float*)d_out;            // 8,388,608 f32
    float* out_k    = out_attn + 8388608L;      // 8,388,608 f32
    float* out_v    = out_k + 8388608L;         // 8,388,608 f32

    // d_out scratch (all regions rewritten before their real contents land):
    char* ob = (char*)d_out;
    bf16* qbuf  = (bf16*)ob;                    // 16,777,216 B ) together exactly
    bf16* kb16  = (bf16*)(ob + 16777216);       //  8,388,608 B ) fill the attn
    bf16* vtb16 = (bf16*)(ob + 25165824);       //  8,388,608 B ) region (33.5MB)
    bf16* wqkvT = (bf16*)(ob + 33554432);       // 50,331,648 B, dead before post_fused
    bf16* hb16  = (bf16*)(ob + 83886080);       // 16,777,216 B, dead before post_fused

    char* ws = (char*)d_ws;                     // total use: 32 MiB
    bf16*  qkvb   = (bf16*)ws;                  // 25,165,824 B
    bf16*  vpb16  = (bf16*)(ws + 25165824);     //  8,388,608 B
    bf16*  oheads = (bf16*)ws;                  // 16,777,216 B (qkvb dead)
    bf16*  osum   = (bf16*)(ws + 16777216);     //  4,194,304 B (qkvb dead)
    bf16*  woT    = (bf16*)(ws + 25165824);     //  8,388,608 B (vpb16 dead)

    // 1. prep: hidden f32->bf16 (4096 blocks) + w_qkv transpose (6144 blocks)
    prep<<<dim3(10240), 256, 0, stream>>>(hidden, hb16, w_qkv, wqkvT);
    // 2. qkv = hidden @ w_qkv (bf16 out); 256 blocks (8 x 32 tiles of 256x192)
    gemm_qkv<<<dim3(256), 512, 0, stream>>>(hb16, wqkvT, qkvb, QKV_N, HID);
    // 3. post_fused: cache copy (skip new rows; 8192 blocks) + rmsnorm/rope/
    //    scatter (2048 blocks).  Disjoint writes -> race-free single launch.
    post_fused<<<dim3(10240), 256, 0, stream>>>(kc_in, vc_in, qkvb, rope_cs,
                                                kvstart, qnw, knw, qbuf,
                                                out_k, out_v, kb16, vpb16);
    // 4. V present (2048,128) -> V^T (128,2048) per (b,hk)
    transpose_bf16<<<dim3(2, 32, 16), 256, 0, stream>>>(vpb16, vtb16, SEQK, HD,
                                                        (long)SEQK * HD, (long)SEQK * HD);
    // 5. w_o (1024,4096) f32 -> woT (4096,1024) bf16  [vpb16 slot, now dead]
    transpose_f2b<<<dim3(64, 16), 256, 0, stream>>>(w_o, woT, 1024, HID);
    // 6. flash attention v4 (r8 version) -> per-head O (bf16)
    attn_fwd<<<dim3(8, NH, NB), 256, 0, stream>>>(qbuf, kb16, vtb16, oheads);
    // 7. sum over GQA groups -> (B,Q,1024) bf16
    group_sum<<<dim3(1024), 256, 0, stream>>>(oheads, osum);
    // 8. attn_output = osum @ w_o -> d_out (fp32); 512 blocks (16 x 32)
    gemm_bb<true><<<dim3(512), 256, 0, stream>>>(osum, woT, out_attn, 2048, HID, 1024, 32);
}